// Round 1
// baseline (512.119 us; speedup 1.0000x reference)
//
#include <hip/hip_runtime.h>

typedef __bf16 bf16;
typedef __bf16 bf16x8 __attribute__((ext_vector_type(8)));
typedef __bf16 bf16x4 __attribute__((ext_vector_type(4)));
typedef float  f32x4  __attribute__((ext_vector_type(4)));

__device__ __forceinline__ f32x4 mfma16(bf16x8 a, bf16x8 b, f32x4 c) {
    return __builtin_amdgcn_mfma_f32_16x16x32_bf16(a, b, c, 0, 0, 0);
}

__device__ __forceinline__ void gll16(const bf16* g, bf16* l) {
    __builtin_amdgcn_global_load_lds(
        (const __attribute__((address_space(1))) void*)g,
        (__attribute__((address_space(3))) void*)l, 16, 0, 0);
}

// ---------------- K0: weight repack ----------------
// BqT[c'][k] = qkv_w[k][h*192+e*3]*0.125 (c'=h*64+e), kvWT[c2][k] (c2=t*128+kk*64+e -> col t*192+e*3+1+kk),
// projWT[c'][k] = proj_w[k][c'], bq scaled, bkv.
__global__ __launch_bounds__(256) void prep_weights(
    const float* __restrict__ qkv_w, const float* __restrict__ qkv_b,
    const float* __restrict__ proj_w,
    bf16* __restrict__ BqT, bf16* __restrict__ kvWT, bf16* __restrict__ projWT,
    float* __restrict__ bq, float* __restrict__ bkv)
{
    int i = blockIdx.x * 256 + threadIdx.x;
    if (i < 262144) {
        int c_ = i >> 9, k = i & 511;
        int c = (c_ >> 6) * 192 + (c_ & 63) * 3;
        BqT[i] = (bf16)(qkv_w[k * 1536 + c] * 0.125f);
        return;
    }
    i -= 262144;
    if (i < 131072) {
        int c2 = i >> 9, k = i & 511;
        int t = c2 >> 7, kk = (c2 >> 6) & 1, e = c2 & 63;
        int c = t * 192 + e * 3 + 1 + kk;
        kvWT[i] = (bf16)(qkv_w[k * 1536 + c]);
        return;
    }
    i -= 131072;
    if (i < 262144) {
        int c_ = i >> 9, k = i & 511;
        projWT[i] = (bf16)(proj_w[k * 512 + c_]);
        return;
    }
    i -= 262144;
    if (i < 512) {
        bq[i] = qkv_b[(i >> 6) * 192 + (i & 63) * 3] * 0.125f;
        return;
    }
    i -= 512;
    if (i < 256) {
        int t = i >> 7, kk = (i >> 6) & 1, e = i & 63;
        bkv[i] = qkv_b[t * 192 + e * 3 + 1 + kk];
    }
}

// ---------------- K1: x' = x + rel@pe_w + pe_b -> bf16 ----------------
__global__ __launch_bounds__(256) void xprep(
    const float* __restrict__ x, const float* __restrict__ pos,
    const float* __restrict__ pe_w, const float* __restrict__ pe_b,
    bf16* __restrict__ xp)
{
    const int ball = blockIdx.x;
    const int tid = threadIdx.x;
    const size_t tok0 = (size_t)ball * 64;

    __shared__ float pw[1536];
    __shared__ float pb[512];
    __shared__ float pp[64][3];
    __shared__ float mean[3];

    for (int i = tid; i < 1536; i += 256) pw[i] = pe_w[i];
    for (int i = tid; i < 512; i += 256) pb[i] = pe_b[i];
    if (tid < 64) {
        pp[tid][0] = pos[(tok0 + tid) * 3 + 0];
        pp[tid][1] = pos[(tok0 + tid) * 3 + 1];
        pp[tid][2] = pos[(tok0 + tid) * 3 + 2];
    }
    __syncthreads();
    if (tid < 3) {
        float s = 0.f;
        #pragma unroll
        for (int i = 0; i < 64; ++i) s += pp[i][tid];
        mean[tid] = s * (1.0f / 64.0f);
    }
    __syncthreads();

    const float4* x4 = (const float4*)(x + tok0 * 512);
    bf16* op = xp + tok0 * 512;
    #pragma unroll 4
    for (int it = 0; it < 32; ++it) {
        int flat = it * 256 + tid;
        int row = flat >> 7;
        int c = (flat & 127) * 4;
        float4 xv = x4[flat];
        float r0 = pp[row][0] - mean[0];
        float r1 = pp[row][1] - mean[1];
        float r2 = pp[row][2] - mean[2];
        float v0 = xv.x + r0 * pw[c + 0] + r1 * pw[512 + c + 0] + r2 * pw[1024 + c + 0] + pb[c + 0];
        float v1 = xv.y + r0 * pw[c + 1] + r1 * pw[512 + c + 1] + r2 * pw[1024 + c + 1] + pb[c + 1];
        float v2 = xv.z + r0 * pw[c + 2] + r1 * pw[512 + c + 2] + r2 * pw[1024 + c + 2] + pb[c + 2];
        float v3 = xv.w + r0 * pw[c + 3] + r1 * pw[512 + c + 3] + r2 * pw[1024 + c + 3] + pb[c + 3];
        bf16x4 ov = { (bf16)v0, (bf16)v1, (bf16)v2, (bf16)v3 };
        *(bf16x4*)(op + (size_t)flat * 4) = ov;
    }
}

// ---------------- GEMM: C[M x 512] = A[M x 512] * Bt[512 x 512]^T + bias ----------------
// EPI=0: bf16 out; EPI=1: f32 out. 128x128 tile, 4 waves, BK=64, global_load_lds,
// XOR-swizzle (slot ^= row&7 on 16B chunks) applied on source addr + read addr (LDS dest linear).
template<int EPI>
__global__ __launch_bounds__(256) void gemm_bt(
    const bf16* __restrict__ A, const bf16* __restrict__ Bt,
    const float* __restrict__ bias, void* __restrict__ Cv)
{
    const int bid = blockIdx.x;
    const int ct = bid & 3;
    const int rt = bid >> 2;
    const int row0 = rt * 128, col0 = ct * 128;
    const int tid = threadIdx.x;
    const int w = tid >> 6, l = tid & 63;
    const int wr = w >> 1, wc = w & 1;
    const int l15 = l & 15, lg = l >> 4;

    __shared__ __align__(16) bf16 As[128 * 64];
    __shared__ __align__(16) bf16 Bs[128 * 64];

    f32x4 acc[4][4] = {};

    int srow[4], scol[4];
    #pragma unroll
    for (int j = 0; j < 4; ++j) {
        int chunk = w * 4 + j;
        int o = chunk * 512 + l * 8;
        int r = o >> 6;
        int slot = (o & 63) >> 3;
        srow[j] = r;
        scol[j] = ((slot ^ (r & 7)) << 3);
    }

    for (int ks = 0; ks < 512; ks += 64) {
        #pragma unroll
        for (int j = 0; j < 4; ++j) {
            int chunk = w * 4 + j;
            gll16(A  + (size_t)(row0 + srow[j]) * 512 + ks + scol[j], &As[chunk * 512]);
            gll16(Bt + (size_t)(col0 + srow[j]) * 512 + ks + scol[j], &Bs[chunk * 512]);
        }
        __syncthreads();
        #pragma unroll
        for (int kk = 0; kk < 2; ++kk) {
            bf16x8 a[4], b[4];
            #pragma unroll
            for (int mi = 0; mi < 4; ++mi) {
                int r = wr * 64 + mi * 16 + l15;
                int slot = (kk * 4 + lg) ^ (r & 7);
                a[mi] = *(const bf16x8*)&As[r * 64 + slot * 8];
            }
            #pragma unroll
            for (int ni = 0; ni < 4; ++ni) {
                int r = wc * 64 + ni * 16 + l15;
                int slot = (kk * 4 + lg) ^ (r & 7);
                b[ni] = *(const bf16x8*)&Bs[r * 64 + slot * 8];
            }
            #pragma unroll
            for (int mi = 0; mi < 4; ++mi)
                #pragma unroll
                for (int ni = 0; ni < 4; ++ni)
                    acc[mi][ni] = mfma16(a[mi], b[ni], acc[mi][ni]);
        }
        __syncthreads();
    }

    #pragma unroll
    for (int mi = 0; mi < 4; ++mi) {
        #pragma unroll
        for (int ni = 0; ni < 4; ++ni) {
            int col = col0 + wc * 64 + ni * 16 + l15;
            float bv = bias[col];
            int rbase = row0 + wr * 64 + mi * 16 + lg * 4;
            #pragma unroll
            for (int r = 0; r < 4; ++r) {
                float vv = acc[mi][ni][r] + bv;
                if (EPI == 0) ((bf16*)Cv)[(size_t)(rbase + r) * 512 + col] = (bf16)vv;
                else          ((float*)Cv)[(size_t)(rbase + r) * 512 + col] = vv;
            }
        }
    }
}

// ---------------- K3: k_sel / v_selT for the 1024 selected tokens ----------------
__global__ __launch_bounds__(256) void kv_proj(
    const bf16* __restrict__ xp, const bf16* __restrict__ kvWT,
    const float* __restrict__ bkv, bf16* __restrict__ ksel, bf16* __restrict__ vselT)
{
    const int bid = blockIdx.x;      // 1024 = 2 b * 8 balls * 64 m2
    const int b = bid >> 9;
    const int ball = (bid >> 6) & 7;
    const int m2 = bid & 63;
    const size_t tok = (size_t)b * 65536 + ball * 64 + m2;
    const int tid = threadIdx.x;

    __shared__ __align__(16) bf16 xrow[512];
    xrow[tid] = xp[tok * 512 + tid];
    xrow[tid + 256] = xp[tok * 512 + tid + 256];
    __syncthreads();

    float acc = 0.f;
    const bf16* wrp = kvWT + (size_t)tid * 512;
    #pragma unroll 8
    for (int k = 0; k < 512; k += 8) {
        bf16x8 wv = *(const bf16x8*)(wrp + k);
        bf16x8 xv = *(const bf16x8*)(&xrow[k]);
        #pragma unroll
        for (int j = 0; j < 8; ++j) acc += (float)xv[j] * (float)wv[j];
    }
    acc += bkv[tid];
    int t = tid >> 7, kk = (tid >> 6) & 1, e = tid & 63;
    if (kk == 0)
        ksel[((size_t)(b * 8 + ball) * 128 + t * 64 + m2) * 64 + e] = (bf16)acc;
    else
        vselT[((size_t)(b * 8 + ball) * 64 + e) * 128 + t * 64 + m2] = (bf16)acc;
}

// ---------------- K4: attention (128 fixed KV per (b,h)) ----------------
__global__ __launch_bounds__(256) void attn_k(
    const bf16* __restrict__ q, const bf16* __restrict__ ksel,
    const bf16* __restrict__ vselT, bf16* __restrict__ attno)
{
    const int bid = blockIdx.x;      // 16384 = 16 bh * 1024 qtiles
    const int qt = bid & 1023;
    const int bh = bid >> 10;
    const int b = bh >> 3;
    const int h = bh & 7;
    const int tid = threadIdx.x;
    const int w = tid >> 6;
    const int l = tid & 63;
    const int l15 = l & 15, lg = l >> 4;

    __shared__ __align__(16) bf16 Ks[128][72];
    __shared__ __align__(16) bf16 Vt[64][136];
    __shared__ __align__(16) bf16 Pl[4][16][136];

    const bf16* kg = ksel + (size_t)(b * 8 + h) * 128 * 64;
    #pragma unroll
    for (int it = 0; it < 8; ++it) {
        int i = it * 256 + tid;
        int r = i >> 4, c4 = (i & 15) * 4;
        *(bf16x4*)&Ks[r][c4] = *(const bf16x4*)(kg + r * 64 + c4);
    }
    const bf16* vg = vselT + (size_t)(b * 8 + h) * 64 * 128;
    #pragma unroll
    for (int it = 0; it < 8; ++it) {
        int i = it * 256 + tid;
        int r = i >> 5, c4 = (i & 31) * 4;
        *(bf16x4*)&Vt[r][c4] = *(const bf16x4*)(vg + r * 128 + c4);
    }

    const size_t tokq = (size_t)b * 65536 + (size_t)qt * 64 + w * 16 + l15;
    const bf16* qp = q + tokq * 512 + h * 64 + lg * 8;
    bf16x8 qa0 = *(const bf16x8*)qp;
    bf16x8 qa1 = *(const bf16x8*)(qp + 32);

    __syncthreads();

    f32x4 s[8];
    #pragma unroll
    for (int kt = 0; kt < 8; ++kt) {
        f32x4 a0 = {0.f, 0.f, 0.f, 0.f};
        a0 = mfma16(qa0, *(const bf16x8*)&Ks[kt * 16 + l15][lg * 8], a0);
        a0 = mfma16(qa1, *(const bf16x8*)&Ks[kt * 16 + l15][32 + lg * 8], a0);
        s[kt] = a0;
    }

    #pragma unroll
    for (int r = 0; r < 4; ++r) {
        float mx = s[0][r];
        #pragma unroll
        for (int kt = 1; kt < 8; ++kt) mx = fmaxf(mx, s[kt][r]);
        mx = fmaxf(mx, __shfl_xor(mx, 1));
        mx = fmaxf(mx, __shfl_xor(mx, 2));
        mx = fmaxf(mx, __shfl_xor(mx, 4));
        mx = fmaxf(mx, __shfl_xor(mx, 8));
        float sum = 0.f;
        #pragma unroll
        for (int kt = 0; kt < 8; ++kt) {
            float p = __expf(s[kt][r] - mx);
            s[kt][r] = p;
            sum += p;
        }
        sum += __shfl_xor(sum, 1);
        sum += __shfl_xor(sum, 2);
        sum += __shfl_xor(sum, 4);
        sum += __shfl_xor(sum, 8);
        float inv = 1.0f / sum;
        int prow = lg * 4 + r;
        #pragma unroll
        for (int kt = 0; kt < 8; ++kt)
            Pl[w][prow][kt * 16 + l15] = (bf16)(s[kt][r] * inv);
    }

    __syncthreads();

    f32x4 o[4] = { {0,0,0,0}, {0,0,0,0}, {0,0,0,0}, {0,0,0,0} };
    #pragma unroll
    for (int kc = 0; kc < 4; ++kc) {
        bf16x8 pa = *(const bf16x8*)&Pl[w][l15][kc * 32 + lg * 8];
        #pragma unroll
        for (int et = 0; et < 4; ++et)
            o[et] = mfma16(pa, *(const bf16x8*)&Vt[et * 16 + l15][kc * 32 + lg * 8], o[et]);
    }

    const size_t tokw = (size_t)b * 65536 + (size_t)qt * 64 + w * 16 + lg * 4;
    #pragma unroll
    for (int et = 0; et < 4; ++et)
        #pragma unroll
        for (int r = 0; r < 4; ++r)
            attno[(tokw + r) * 512 + h * 64 + et * 16 + l15] = (bf16)(o[et][r]);
}

extern "C" void kernel_launch(void* const* d_in, const int* in_sizes, int n_in,
                              void* d_out, int out_size, void* d_ws, size_t ws_size,
                              hipStream_t stream) {
    (void)in_sizes; (void)n_in; (void)out_size; (void)ws_size;
    const float* x      = (const float*)d_in[0];
    const float* pos    = (const float*)d_in[1];
    const float* qkv_w  = (const float*)d_in[2];
    const float* qkv_b  = (const float*)d_in[3];
    const float* proj_w = (const float*)d_in[4];
    const float* proj_b = (const float*)d_in[5];
    const float* pe_w   = (const float*)d_in[6];
    const float* pe_b   = (const float*)d_in[7];

    char* ws = (char*)d_ws;
    bf16*  Z     = (bf16*)(ws);                    // x' (bf16), later reused as attn-out
    bf16*  Q     = (bf16*)(ws + 134217728);
    bf16*  BqT   = (bf16*)(ws + 268435456);
    bf16*  PjT   = (bf16*)(ws + 268959744);
    bf16*  kvWT  = (bf16*)(ws + 269484032);
    bf16*  ksel  = (bf16*)(ws + 269746176);
    bf16*  vselT = (bf16*)(ws + 270008320);
    float* bq    = (float*)(ws + 270270464);
    float* bkv   = (float*)(ws + 270272512);

    prep_weights<<<2563, 256, 0, stream>>>(qkv_w, qkv_b, proj_w, BqT, kvWT, PjT, bq, bkv);
    xprep<<<2048, 256, 0, stream>>>(x, pos, pe_w, pe_b, Z);
    gemm_bt<0><<<4096, 256, 0, stream>>>(Z, BqT, bq, (void*)Q);
    kv_proj<<<1024, 256, 0, stream>>>(Z, kvWT, bkv, ksel, vselT);
    attn_k<<<16384, 256, 0, stream>>>(Q, ksel, vselT, Z);
    gemm_bt<1><<<4096, 256, 0, stream>>>(Z, PjT, proj_b, d_out);
}